// Round 3
// baseline (56.625 us; speedup 1.0000x reference)
//
#include <hip/hip_runtime.h>
#include <hip/hip_bf16.h>

// TT-Rec embedding bag, MI355X. R2 version.
// P=(100,100,100), Q=(4,4,8), R=(1,32,32,1), D=128, B=4096, H=50, n=204800.
//
//   K1 (prep, fused):
//     blocks 0..999      -> AB build, one (i2, i1-group-of-10): core1 col-slice in
//                           VGPRs, core0 via wave-uniform scalar loads. AB bf16 table.
//     blocks 1000..1099  -> Bfrag[i3] prepack (MFMA B-fragment order)
//     block  1100        -> scan lengths -> offsets[B+1]
//   K2 (bag_pool): 2 waves per bag (split indices), readlane offset broadcast,
//     ping-pong software pipeline (groups of 4), LDS combine of the two halves.

#define P0 100
#define P1 100
#define P2 100
#define Q2 8
#define DIM 128
#define NPAIR (P0 * P1)
#define NAB_BLOCKS 1000

typedef __attribute__((ext_vector_type(8))) short short8v;   // 8 bf16
typedef __attribute__((ext_vector_type(4))) float f32x4;

// ---------------- K1: fused prep ----------------
__global__ __launch_bounds__(256) void prep(const int* __restrict__ lengths, int B,
                                            const float* __restrict__ core0,
                                            const float* __restrict__ core1,
                                            const float* __restrict__ core2,
                                            int* __restrict__ offsets,
                                            __hip_bfloat16* __restrict__ bfrag,
                                            __hip_bfloat16* __restrict__ ab) {
    int bid = blockIdx.x;
    int t = threadIdx.x;
    if (bid < NAB_BLOCKS) {
        // ---- AB build: i2 = bid%100, i1 in [ (bid/100)*10, +10 ) ----
        int i2 = bid % P1;
        int g10 = bid / P1;
        int col = t & 127;          // output column = b_*32 + s
        int h = t >> 7;             // wave-uniform: a-rows {2h, 2h+1}
        const float* brow = core1 + (size_t)i2 * 4096;
        float v[32];
#pragma unroll
        for (int r = 0; r < 32; ++r) v[r] = brow[r * 128 + col];   // coalesced
        for (int q = 0; q < 10; ++q) {
            int i1 = g10 * 10 + q;
            const float* arow = core0 + (size_t)i1 * 128;   // uniform -> s_load
            float acc0 = 0.f, acc1 = 0.f;
#pragma unroll
            for (int r = 0; r < 32; ++r) {
                acc0 = fmaf(arow[(2 * h) * 32 + r], v[r], acc0);     // SGPR x VGPR
                acc1 = fmaf(arow[(2 * h + 1) * 32 + r], v[r], acc1);
            }
            __hip_bfloat16* o = ab + (size_t)(i1 * P1 + i2) * 512;
            o[(2 * h) * 128 + col]     = __float2bfloat16(acc0);
            o[(2 * h + 1) * 128 + col] = __float2bfloat16(acc1);
        }
    } else if (bid < NAB_BLOCKS + P2) {
        // ---- Bfrag prepack: lane l holds B[k=(l>>4)*8+j][col=l&15], cols 8..15 dup 0..7.
        // stored element: i3*256 + (l>>4)*64 + (l&7)*8 + j
        if (t < 64 && !(t & 8)) {
            int i3 = bid - NAB_BLOCKS;
            int h = t >> 4, c3 = t & 7;
            const float* crow = core2 + (size_t)i3 * (32 * Q2);
            __hip_bfloat16* o = bfrag + (size_t)i3 * 256 + h * 64 + c3 * 8;
#pragma unroll
            for (int j = 0; j < 8; ++j)
                o[j] = __float2bfloat16(crow[(h * 8 + j) * Q2 + c3]);
        }
    } else {
        // ---- exclusive scan of lengths (single block, 256 threads) ----
        __shared__ int part[256];
        int per = (B + 255) / 256;
        int s = 0;
        for (int k = 0; k < per; ++k) {
            int i = t * per + k;
            s += (i < B) ? lengths[i] : 0;
        }
        part[t] = s;
        __syncthreads();
        for (int d = 1; d < 256; d <<= 1) {
            int vv = (t >= d) ? part[t - d] : 0;
            __syncthreads();
            part[t] += vv;
            __syncthreads();
        }
        int run = part[t] - s;
        for (int k = 0; k < per; ++k) {
            int i = t * per + k;
            if (i < B) { offsets[i] = run; run += lengths[i]; }
        }
        if (t == 255) offsets[B] = part[255];
    }
}

// ---------------- K2: bag pooling via MFMA ----------------
// 256 threads = 4 waves: wave w -> bag = blk*2 + (w>>1), half = w&1.
// Each wave handles half the bag's indices; halves combined through LDS.

#define FETCH(g, fa, fb) {                                          \
    int _j = (g) << 2;                                              \
    int _A0 = __builtin_amdgcn_readlane(abo, _j);                   \
    int _B0 = __builtin_amdgcn_readlane(bfo, _j);                   \
    int _A1 = __builtin_amdgcn_readlane(abo, _j + 1);               \
    int _B1 = __builtin_amdgcn_readlane(bfo, _j + 1);               \
    int _A2 = __builtin_amdgcn_readlane(abo, _j + 2);               \
    int _B2 = __builtin_amdgcn_readlane(bfo, _j + 2);               \
    int _A3 = __builtin_amdgcn_readlane(abo, _j + 3);               \
    int _B3 = __builtin_amdgcn_readlane(bfo, _j + 3);               \
    fa##0 = *(const short8v*)(ab + _A0 + aoff);                     \
    fb##0 = *(const short8v*)(bfrag + _B0 + boff);                  \
    fa##1 = *(const short8v*)(ab + _A1 + aoff);                     \
    fb##1 = *(const short8v*)(bfrag + _B1 + boff);                  \
    fa##2 = *(const short8v*)(ab + _A2 + aoff);                     \
    fb##2 = *(const short8v*)(bfrag + _B2 + boff);                  \
    fa##3 = *(const short8v*)(ab + _A3 + aoff);                     \
    fb##3 = *(const short8v*)(bfrag + _B3 + boff);                  \
}

#define MFMAG(fa, fb, g) {                                                        \
    int _rem = m - ((g) << 2);                                                    \
    acc0 = __builtin_amdgcn_mfma_f32_16x16x32_bf16(fa##0, fb##0, acc0, 0, 0, 0);  \
    if (_rem > 1) acc1 = __builtin_amdgcn_mfma_f32_16x16x32_bf16(fa##1, fb##1, acc1, 0, 0, 0); \
    if (_rem > 2) acc2 = __builtin_amdgcn_mfma_f32_16x16x32_bf16(fa##2, fb##2, acc2, 0, 0, 0); \
    if (_rem > 3) acc3 = __builtin_amdgcn_mfma_f32_16x16x32_bf16(fa##3, fb##3, acc3, 0, 0, 0); \
}

__global__ __launch_bounds__(256) void bag_pool(const int* __restrict__ indices, int n,
                                                const int* __restrict__ offsets, int B,
                                                const char* __restrict__ ab,
                                                const char* __restrict__ bfrag,
                                                float* __restrict__ out) {
    int w = threadIdx.x >> 6;
    int lane = threadIdx.x & 63;
    int bag = blockIdx.x * 2 + (w >> 1);
    int half = w & 1;

    int start = 0, end = 0;
    if (bag < B) {
        start = offsets[bag];
        end = offsets[bag + 1];
        if (bag == B - 1 && end < n) end = n;   // jnp.repeat pads with last bag id
        if (end > n) end = n;
        if (start > n) start = n;
        if (end < start) end = start;
    }
    int cnt = end - start;
    int c0 = (cnt + 1) >> 1;
    int mystart = start + (half ? c0 : 0);
    int mycnt = half ? (cnt - c0) : c0;

    // A fragment: lane l holds A[row=l&15][k=(l>>4)*8+j]; AB row-major [16][32] bf16.
    int aoff = (lane & 15) * 64 + (lane >> 4) * 16;     // bytes
    int boff = (lane >> 4) * 128 + (lane & 7) * 16;     // bytes

    f32x4 acc0 = {0.f, 0.f, 0.f, 0.f};
    f32x4 acc1 = {0.f, 0.f, 0.f, 0.f};
    f32x4 acc2 = {0.f, 0.f, 0.f, 0.f};
    f32x4 acc3 = {0.f, 0.f, 0.f, 0.f};

    for (int cb = 0; cb < mycnt; cb += 64) {
        int m = mycnt - cb;
        if (m > 64) m = 64;
        unsigned idx = 0;
        if (lane < m) idx = (unsigned)indices[mystart + cb + lane];
        unsigned p = idx / 100u;                 // magic-mul
        unsigned i3 = idx - p * 100u;
        int abo = (int)(p << 10);                // AB row byte offset (lanes>=m: 0, safe)
        int bfo = (int)(i3 << 9);                // bfrag row byte offset

        int G = (m + 3) >> 2;
        short8v fa0, fa1, fa2, fa3, fb0, fb1, fb2, fb3;
        short8v ga0, ga1, ga2, ga3, gb0, gb1, gb2, gb3;
        FETCH(0, fa, fb);
        int g = 0;
        while (true) {
            if (g + 1 < G) FETCH(g + 1, ga, gb);
            MFMAG(fa, fb, g);
            ++g; if (g >= G) break;
            if (g + 1 < G) FETCH(g + 1, fa, fb);
            MFMAG(ga, gb, g);
            ++g; if (g >= G) break;
        }
    }
    f32x4 acc = (acc0 + acc1) + (acc2 + acc3);

    // combine halves through LDS
    __shared__ f32x4 red[2][64];
    if (half) red[w >> 1][lane] = acc;
    __syncthreads();
    if (!half) {
        acc += red[w >> 1][lane];
        // D layout: col = lane&15, row = (lane>>4)*4 + q; cols 0..7 useful.
        int col = lane & 15;
        if (bag < B && col < 8) {
            int rb = (lane >> 4) * 4;
            float* orow = out + (size_t)bag * DIM;
#pragma unroll
            for (int q = 0; q < 4; ++q)
                orow[(rb + q) * 8 + col] = acc[q];   // d = m*8 + c3
        }
    }
}

// ---------------- fallback (ws too small): direct VALU, equal-length bags ----------------
__global__ __launch_bounds__(128) void fallback_pool(const int* __restrict__ indices,
                                                     int n, int B,
                                                     const float* __restrict__ core0,
                                                     const float* __restrict__ core1,
                                                     const float* __restrict__ core2,
                                                     float* __restrict__ out) {
    int bag = blockIdx.x;
    int d = threadIdx.x;
    int m = d >> 3, c3 = d & 7;
    int a_ = m >> 2, b_ = m & 3;
    int H = n / B;
    float acc = 0.f;
    for (int j = bag * H; j < (bag + 1) * H; ++j) {
        int idx = indices[j];
        int i1 = idx / (P1 * P2);
        int rem = idx - i1 * (P1 * P2);
        int i2 = rem / P2;
        int i3 = rem - i2 * P2;
        const float* a = core0 + (size_t)i1 * 128;
        const float* b = core1 + (size_t)i2 * 4096;
        const float* c = core2 + (size_t)i3 * 256;
        float e = 0.f;
        for (int s = 0; s < 32; ++s) {
            float abv = 0.f;
            for (int r = 0; r < 32; ++r)
                abv += a[a_ * 32 + r] * b[r * 128 + b_ * 32 + s];
            e += abv * c[s * 8 + c3];
        }
        acc += e;
    }
    out[(size_t)bag * DIM + d] = acc;
}

extern "C" void kernel_launch(void* const* d_in, const int* in_sizes, int n_in,
                              void* d_out, int out_size, void* d_ws, size_t ws_size,
                              hipStream_t stream) {
    const int* indices = (const int*)d_in[0];
    const int* lengths = (const int*)d_in[1];
    const float* core0 = (const float*)d_in[2];
    const float* core1 = (const float*)d_in[3];
    const float* core2 = (const float*)d_in[4];
    float* out = (float*)d_out;
    int n = in_sizes[0];
    int B = in_sizes[1];

    const size_t OFF_OFFSETS = 0;                       // (B+1) ints
    const size_t OFF_BFRAG = 32768;                     // 100 * 512 B
    const size_t OFF_AB = 131072;                       // 10000 * 1024 B
    const size_t REQ = OFF_AB + (size_t)NPAIR * 1024;

    if (ws_size >= REQ) {
        int* offsets = (int*)((char*)d_ws + OFF_OFFSETS);
        __hip_bfloat16* bfragp = (__hip_bfloat16*)((char*)d_ws + OFF_BFRAG);
        __hip_bfloat16* abt = (__hip_bfloat16*)((char*)d_ws + OFF_AB);

        prep<<<NAB_BLOCKS + P2 + 1, 256, 0, stream>>>(lengths, B, core0, core1, core2,
                                                      offsets, bfragp, abt);
        bag_pool<<<(B + 1) / 2, 256, 0, stream>>>(indices, n, offsets, B,
                                                  (const char*)abt, (const char*)bfragp, out);
    } else {
        fallback_pool<<<B, 128, 0, stream>>>(indices, n, B, core0, core1, core2, out);
    }
}

// Round 4
// 44.170 us; speedup vs baseline: 1.2820x; 1.2820x over previous
//
#include <hip/hip_runtime.h>
#include <hip/hip_bf16.h>

// TT-Rec embedding bag, MI355X. R3 version.
// P=(100,100,100), Q=(4,4,8), R=(1,32,32,1), D=128, B=4096, H=50, n=204800.
//
//   K1 (prep, fused — R1-exact known-good):
//     block 0           -> scan lengths -> offsets[B+1]
//     blocks 1..100     -> Bfrag[i3] prepack (MFMA B-fragment order)
//     blocks 101..10100 -> AB[pair][16][32] bf16 = a(4x32)@b(32x128)
//   K2 (bag_pool): 2 waves per bag (25 idx each), R1-style clean inner loop
//     (shfl broadcast, unconditional 4-deep MFMA groups), LDS combine,
//     __launch_bounds__(256,6) for 24 waves/CU.

#define P0 100
#define P1 100
#define P2 100
#define Q0 4
#define Q1 4
#define Q2 8
#define DIM 128
#define NPAIR (P0 * P1)

typedef __attribute__((ext_vector_type(8))) short short8v;   // 8 bf16
typedef __attribute__((ext_vector_type(4))) float f32x4;

// ---------------- K1: fused prep (R1-exact) ----------------
__global__ __launch_bounds__(128) void prep(const int* __restrict__ lengths, int B,
                                            const float* __restrict__ core0,
                                            const float* __restrict__ core1,
                                            const float* __restrict__ core2,
                                            int* __restrict__ offsets,
                                            __hip_bfloat16* __restrict__ bfrag,
                                            __hip_bfloat16* __restrict__ ab) {
    int bid = blockIdx.x;
    int t = threadIdx.x;
    if (bid == 0) {
        // ---- exclusive scan of lengths (single block, 128 threads) ----
        __shared__ int part[128];
        int per = (B + 127) / 128;
        int s = 0;
        for (int k = 0; k < per; ++k) {
            int i = t * per + k;
            s += (i < B) ? lengths[i] : 0;
        }
        part[t] = s;
        __syncthreads();
        for (int d = 1; d < 128; d <<= 1) {
            int v = (t >= d) ? part[t - d] : 0;
            __syncthreads();
            part[t] += v;
            __syncthreads();
        }
        int run = part[t] - s;
        for (int k = 0; k < per; ++k) {
            int i = t * per + k;
            if (i < B) { offsets[i] = run; run += lengths[i]; }
        }
        if (t == 127) offsets[B] = part[127];
    } else if (bid <= P2) {
        // ---- Bfrag prepack: lane l holds B[k=(l>>4)*8+j][col=l&15], cols 8..15 dup 0..7.
        // stored element: i3*256 + (l>>4)*64 + (l&7)*8 + j  (unduplicated, 512B/row)
        if (t < 64 && !(t & 8)) {
            int i3 = bid - 1;
            int h = t >> 4, c3 = t & 7;
            const float* crow = core2 + (size_t)i3 * (32 * Q2);
            __hip_bfloat16* o = bfrag + (size_t)i3 * 256 + h * 64 + c3 * 8;
#pragma unroll
            for (int j = 0; j < 8; ++j)
                o[j] = __float2bfloat16(crow[(h * 8 + j) * Q2 + c3]);
        }
    } else {
        // ---- AB build: one (i1,i2) pair per block ----
        int p12 = bid - 1 - P2;
        int i1 = p12 / P1;
        int i2 = p12 - i1 * P1;
        __shared__ float a_lds[128];
        a_lds[t] = core0[i1 * 128 + t];
        __syncthreads();
        const float* brow = core1 + (size_t)i2 * 4096;
        float acc0 = 0.f, acc1 = 0.f, acc2 = 0.f, acc3 = 0.f;
#pragma unroll
        for (int r = 0; r < 32; ++r) {
            float bv = brow[r * 128 + t];          // coalesced, core1 L2-resident
            acc0 += a_lds[r] * bv;                 // uniform addr -> LDS broadcast
            acc1 += a_lds[32 + r] * bv;
            acc2 += a_lds[64 + r] * bv;
            acc3 += a_lds[96 + r] * bv;
        }
        __hip_bfloat16* o = ab + (size_t)p12 * 512;
        o[t]       = __float2bfloat16(acc0);
        o[128 + t] = __float2bfloat16(acc1);
        o[256 + t] = __float2bfloat16(acc2);
        o[384 + t] = __float2bfloat16(acc3);
    }
}

// ---------------- K2: bag pooling via MFMA ----------------
// 256 threads = 4 waves: wave w -> bag = blk*2 + (w>>1), half = w&1.
// Each wave handles half the bag's indices; halves combined through LDS.
__global__ __launch_bounds__(256, 6) void bag_pool(const int* __restrict__ indices, int n,
                                                   const int* __restrict__ offsets, int B,
                                                   const char* __restrict__ ab,
                                                   const char* __restrict__ bfrag,
                                                   float* __restrict__ out) {
    int w = threadIdx.x >> 6;
    int lane = threadIdx.x & 63;
    int bag = blockIdx.x * 2 + (w >> 1);
    int half = w & 1;

    int start = 0, end = 0;
    if (bag < B) {
        start = offsets[bag];
        end = offsets[bag + 1];
        if (bag == B - 1 && end < n) end = n;   // jnp.repeat pads with last bag id
        if (end > n) end = n;
        if (start > n) start = n;
        if (end < start) end = start;
    }
    int cnt = end - start;
    int c0 = (cnt + 1) >> 1;
    int mystart = start + (half ? c0 : 0);
    int mycnt = half ? (cnt - c0) : c0;

    // A fragment: lane l holds A[row=l&15][k=(l>>4)*8+j]; AB row-major [16][32] bf16.
    int aoff = (lane & 15) * 64 + (lane >> 4) * 16;     // bytes
    int boff = (lane >> 4) * 128 + (lane & 7) * 16;     // bytes

    f32x4 acc0 = {0.f, 0.f, 0.f, 0.f};
    f32x4 acc1 = {0.f, 0.f, 0.f, 0.f};
    f32x4 acc2 = {0.f, 0.f, 0.f, 0.f};
    f32x4 acc3 = {0.f, 0.f, 0.f, 0.f};

    for (int cb = 0; cb < mycnt; cb += 64) {
        int m = mycnt - cb;
        if (m > 64) m = 64;
        // lane j owns index (cb+j): load once, decompose once.
        unsigned idx = 0;
        if (lane < m) idx = (unsigned)indices[mystart + cb + lane];
        unsigned p = idx / 100u;                 // magic-mul, 2 VALU
        unsigned i3 = idx - p * 100u;
        int abo = (int)(p << 10);                // AB row byte offset
        int bfo = (int)(i3 << 9);                // bfrag row byte offset

        int j = 0;
        for (; j + 3 < m; j += 4) {
            int A0 = __shfl(abo, j),     B0 = __shfl(bfo, j);
            int A1 = __shfl(abo, j + 1), B1 = __shfl(bfo, j + 1);
            int A2 = __shfl(abo, j + 2), B2 = __shfl(bfo, j + 2);
            int A3 = __shfl(abo, j + 3), B3 = __shfl(bfo, j + 3);
            short8v a0 = *(const short8v*)(ab + A0 + aoff);
            short8v b0 = *(const short8v*)(bfrag + B0 + boff);
            short8v a1 = *(const short8v*)(ab + A1 + aoff);
            short8v b1 = *(const short8v*)(bfrag + B1 + boff);
            short8v a2 = *(const short8v*)(ab + A2 + aoff);
            short8v b2 = *(const short8v*)(bfrag + B2 + boff);
            short8v a3 = *(const short8v*)(ab + A3 + aoff);
            short8v b3 = *(const short8v*)(bfrag + B3 + boff);
            acc0 = __builtin_amdgcn_mfma_f32_16x16x32_bf16(a0, b0, acc0, 0, 0, 0);
            acc1 = __builtin_amdgcn_mfma_f32_16x16x32_bf16(a1, b1, acc1, 0, 0, 0);
            acc2 = __builtin_amdgcn_mfma_f32_16x16x32_bf16(a2, b2, acc2, 0, 0, 0);
            acc3 = __builtin_amdgcn_mfma_f32_16x16x32_bf16(a3, b3, acc3, 0, 0, 0);
        }
        for (; j < m; ++j) {
            int A0 = __shfl(abo, j), B0 = __shfl(bfo, j);
            short8v a0 = *(const short8v*)(ab + A0 + aoff);
            short8v b0 = *(const short8v*)(bfrag + B0 + boff);
            acc0 = __builtin_amdgcn_mfma_f32_16x16x32_bf16(a0, b0, acc0, 0, 0, 0);
        }
    }
    f32x4 acc = (acc0 + acc1) + (acc2 + acc3);

    // combine halves through LDS (all waves reach the barrier)
    __shared__ f32x4 red[2][64];
    if (half) red[w >> 1][lane] = acc;
    __syncthreads();
    if (!half) {
        acc += red[w >> 1][lane];
        // D layout: col = lane&15, row = (lane>>4)*4 + q; cols 0..7 useful.
        int col = lane & 15;
        if (bag < B && col < 8) {
            int rb = (lane >> 4) * 4;
            float* orow = out + (size_t)bag * DIM;
#pragma unroll
            for (int q = 0; q < 4; ++q)
                orow[(rb + q) * 8 + col] = acc[q];   // d = m*8 + c3
        }
    }
}

// ---------------- fallback (ws too small): direct VALU, equal-length bags ----------------
__global__ __launch_bounds__(128) void fallback_pool(const int* __restrict__ indices,
                                                     int n, int B,
                                                     const float* __restrict__ core0,
                                                     const float* __restrict__ core1,
                                                     const float* __restrict__ core2,
                                                     float* __restrict__ out) {
    int bag = blockIdx.x;
    int d = threadIdx.x;
    int m = d >> 3, c3 = d & 7;
    int a_ = m >> 2, b_ = m & 3;
    int H = n / B;
    float acc = 0.f;
    for (int j = bag * H; j < (bag + 1) * H; ++j) {
        int idx = indices[j];
        int i1 = idx / (P1 * P2);
        int rem = idx - i1 * (P1 * P2);
        int i2 = rem / P2;
        int i3 = rem - i2 * P2;
        const float* a = core0 + (size_t)i1 * 128;
        const float* b = core1 + (size_t)i2 * 4096;
        const float* c = core2 + (size_t)i3 * 256;
        float e = 0.f;
        for (int s = 0; s < 32; ++s) {
            float abv = 0.f;
            for (int r = 0; r < 32; ++r)
                abv += a[a_ * 32 + r] * b[r * 128 + b_ * 32 + s];
            e += abv * c[s * 8 + c3];
        }
        acc += e;
    }
    out[(size_t)bag * DIM + d] = acc;
}

extern "C" void kernel_launch(void* const* d_in, const int* in_sizes, int n_in,
                              void* d_out, int out_size, void* d_ws, size_t ws_size,
                              hipStream_t stream) {
    const int* indices = (const int*)d_in[0];
    const int* lengths = (const int*)d_in[1];
    const float* core0 = (const float*)d_in[2];
    const float* core1 = (const float*)d_in[3];
    const float* core2 = (const float*)d_in[4];
    float* out = (float*)d_out;
    int n = in_sizes[0];
    int B = in_sizes[1];

    const size_t OFF_OFFSETS = 0;                       // (B+1) ints
    const size_t OFF_BFRAG = 32768;                     // 100 * 512 B
    const size_t OFF_AB = 131072;                       // 10000 * 1024 B
    const size_t REQ = OFF_AB + (size_t)NPAIR * 1024;

    if (ws_size >= REQ) {
        int* offsets = (int*)((char*)d_ws + OFF_OFFSETS);
        __hip_bfloat16* bfragp = (__hip_bfloat16*)((char*)d_ws + OFF_BFRAG);
        __hip_bfloat16* abt = (__hip_bfloat16*)((char*)d_ws + OFF_AB);

        prep<<<1 + P2 + NPAIR, 128, 0, stream>>>(lengths, B, core0, core1, core2,
                                                 offsets, bfragp, abt);
        bag_pool<<<(B + 1) / 2, 256, 0, stream>>>(indices, n, offsets, B,
                                                  (const char*)abt, (const char*)bfragp, out);
    } else {
        fallback_pool<<<B, 128, 0, stream>>>(indices, n, B, core0, core1, core2, out);
    }
}

// Round 5
// 43.265 us; speedup vs baseline: 1.3088x; 1.0209x over previous
//
#include <hip/hip_runtime.h>
#include <hip/hip_bf16.h>

// TT-Rec embedding bag, MI355X. R4 version.
// P=(100,100,100), Q=(4,4,8), R=(1,32,32,1), D=128, B=4096, H=50, n=204800.
//
//   K1 (prep, fused):
//     block 0           -> scan lengths -> offsets[B+1]
//     blocks 1..100     -> Bfrag[i3] prepack for pool (MFMA B-fragment order)
//     blocks 101..300   -> AB table via MFMA GEMM: per i2, C(400x128) =
//                          core0_stacked(400x32) @ b_i2(32x128), K=32 in ONE
//                          mfma_f32_16x16x32_bf16 per 16x16 tile. One (i2,ct)
//                          per wave: B-frag in regs, 25 row-tiles looped.
//   K2 (bag_pool): R4-exact (2 waves/bag, shfl broadcast, 4-deep MFMA groups).

#define P0 100
#define P1 100
#define P2 100
#define Q0 4
#define Q1 4
#define Q2 8
#define DIM 128
#define NPAIR (P0 * P1)

typedef __attribute__((ext_vector_type(8))) short short8v;   // 8 bf16
typedef __attribute__((ext_vector_type(4))) float f32x4;

__device__ inline short f2bf(float x) {
    union { __hip_bfloat16 h; short s; } u;
    u.h = __float2bfloat16(x);
    return u.s;
}

// ---------------- K1: fused prep ----------------
__global__ __launch_bounds__(256) void prep(const int* __restrict__ lengths, int B,
                                            const float* __restrict__ core0,
                                            const float* __restrict__ core1,
                                            const float* __restrict__ core2,
                                            int* __restrict__ offsets,
                                            __hip_bfloat16* __restrict__ bfrag,
                                            __hip_bfloat16* __restrict__ ab) {
    int bid = blockIdx.x;
    int t = threadIdx.x;
    if (bid == 0) {
        // ---- exclusive scan of lengths (single block, 256 threads) ----
        __shared__ int part[256];
        int per = (B + 255) / 256;
        int s = 0;
        for (int k = 0; k < per; ++k) {
            int i = t * per + k;
            s += (i < B) ? lengths[i] : 0;
        }
        part[t] = s;
        __syncthreads();
        for (int d = 1; d < 256; d <<= 1) {
            int v = (t >= d) ? part[t - d] : 0;
            __syncthreads();
            part[t] += v;
            __syncthreads();
        }
        int run = part[t] - s;
        for (int k = 0; k < per; ++k) {
            int i = t * per + k;
            if (i < B) { offsets[i] = run; run += lengths[i]; }
        }
        if (t == 255) offsets[B] = part[255];
    } else if (bid <= P2) {
        // ---- pool B-frag prepack: lane l holds C[k=(l>>4)*8+j][col=l&15],
        // cols 8..15 duplicate 0..7; stored: i3*256 + (l>>4)*64 + (l&7)*8 + j
        if (t < 64 && !(t & 8)) {
            int i3 = bid - 1;
            int h = t >> 4, c3 = t & 7;
            const float* crow = core2 + (size_t)i3 * (32 * Q2);
            __hip_bfloat16* o = bfrag + (size_t)i3 * 256 + h * 64 + c3 * 8;
#pragma unroll
            for (int j = 0; j < 8; ++j)
                o[j] = __float2bfloat16(crow[(h * 8 + j) * Q2 + c3]);
        }
    } else {
        // ---- AB build via MFMA: g in [0,200): i2 = g>>1, wave ct = (g&1)*4+w ----
        int g = bid - 1 - P2;
        int i2 = g >> 1;
        int w = t >> 6, lane = t & 63;
        int ct = (g & 1) * 4 + w;            // 0..7 (column tile of 16)
        int h = lane >> 4;                   // k-half (0..3) -> k = h*8+j
        int c16 = lane & 15;

        // B-frag once per wave: B[k][col] = core1[i2][k*128 + col], col = ct*16+c16
        const float* bbase = core1 + (size_t)i2 * 4096 + (h * 8) * 128 + ct * 16 + c16;
        short8v bfr;
#pragma unroll
        for (int j = 0; j < 8; ++j) bfr[j] = f2bf(bbase[j * 128]);

        int col = ct * 16 + c16;
        for (int rt = 0; rt < 25; ++rt) {
            // A-frag: row R = rt*16 + c16 -> i1 = rt*4 + (c16>>2), a_ = c16&3;
            // elements k = h*8 + 0..7 contiguous in core0 row.
            const float* abase = core0 + (size_t)(rt * 4 + (c16 >> 2)) * 128
                                 + (c16 & 3) * 32 + h * 8;
            f32x4 x0 = *(const f32x4*)abase;
            f32x4 x1 = *(const f32x4*)(abase + 4);
            short8v afr;
#pragma unroll
            for (int j = 0; j < 4; ++j) { afr[j] = f2bf(x0[j]); afr[j + 4] = f2bf(x1[j]); }

            f32x4 d = __builtin_amdgcn_mfma_f32_16x16x32_bf16(
                afr, bfr, (f32x4){0.f, 0.f, 0.f, 0.f}, 0, 0, 0);

            // D: row = h*4 + q (tile), col = ct*16 + c16.
            // R = rt*16 + h*4 + q -> i1 = rt*4 + h, a_ = q.
            // AB[pair][m=a_*4+b_][s]: elem off = pair*512 + q*128 + (col>>5)*32 + (col&31)
            __hip_bfloat16* dst = ab + (size_t)((rt * 4 + h) * P1 + i2) * 512
                                  + (col >> 5) * 32 + (col & 31);
#pragma unroll
            for (int q = 0; q < 4; ++q) dst[q * 128] = __float2bfloat16(d[q]);
        }
    }
}

// ---------------- K2: bag pooling via MFMA (R4-exact) ----------------
// 256 threads = 4 waves: wave w -> bag = blk*2 + (w>>1), half = w&1.
__global__ __launch_bounds__(256, 6) void bag_pool(const int* __restrict__ indices, int n,
                                                   const int* __restrict__ offsets, int B,
                                                   const char* __restrict__ ab,
                                                   const char* __restrict__ bfrag,
                                                   float* __restrict__ out) {
    int w = threadIdx.x >> 6;
    int lane = threadIdx.x & 63;
    int bag = blockIdx.x * 2 + (w >> 1);
    int half = w & 1;

    int start = 0, end = 0;
    if (bag < B) {
        start = offsets[bag];
        end = offsets[bag + 1];
        if (bag == B - 1 && end < n) end = n;   // jnp.repeat pads with last bag id
        if (end > n) end = n;
        if (start > n) start = n;
        if (end < start) end = start;
    }
    int cnt = end - start;
    int c0 = (cnt + 1) >> 1;
    int mystart = start + (half ? c0 : 0);
    int mycnt = half ? (cnt - c0) : c0;

    // A fragment: lane l holds A[row=l&15][k=(l>>4)*8+j]; AB row-major [16][32] bf16.
    int aoff = (lane & 15) * 64 + (lane >> 4) * 16;     // bytes
    int boff = (lane >> 4) * 128 + (lane & 7) * 16;     // bytes

    f32x4 acc0 = {0.f, 0.f, 0.f, 0.f};
    f32x4 acc1 = {0.f, 0.f, 0.f, 0.f};
    f32x4 acc2 = {0.f, 0.f, 0.f, 0.f};
    f32x4 acc3 = {0.f, 0.f, 0.f, 0.f};

    for (int cb = 0; cb < mycnt; cb += 64) {
        int m = mycnt - cb;
        if (m > 64) m = 64;
        unsigned idx = 0;
        if (lane < m) idx = (unsigned)indices[mystart + cb + lane];
        unsigned p = idx / 100u;                 // magic-mul
        unsigned i3 = idx - p * 100u;
        int abo = (int)(p << 10);                // AB row byte offset
        int bfo = (int)(i3 << 9);                // bfrag row byte offset

        int j = 0;
        for (; j + 3 < m; j += 4) {
            int A0 = __shfl(abo, j),     B0 = __shfl(bfo, j);
            int A1 = __shfl(abo, j + 1), B1 = __shfl(bfo, j + 1);
            int A2 = __shfl(abo, j + 2), B2 = __shfl(bfo, j + 2);
            int A3 = __shfl(abo, j + 3), B3 = __shfl(bfo, j + 3);
            short8v a0 = *(const short8v*)(ab + A0 + aoff);
            short8v b0 = *(const short8v*)(bfrag + B0 + boff);
            short8v a1 = *(const short8v*)(ab + A1 + aoff);
            short8v b1 = *(const short8v*)(bfrag + B1 + boff);
            short8v a2 = *(const short8v*)(ab + A2 + aoff);
            short8v b2 = *(const short8v*)(bfrag + B2 + boff);
            short8v a3 = *(const short8v*)(ab + A3 + aoff);
            short8v b3 = *(const short8v*)(bfrag + B3 + boff);
            acc0 = __builtin_amdgcn_mfma_f32_16x16x32_bf16(a0, b0, acc0, 0, 0, 0);
            acc1 = __builtin_amdgcn_mfma_f32_16x16x32_bf16(a1, b1, acc1, 0, 0, 0);
            acc2 = __builtin_amdgcn_mfma_f32_16x16x32_bf16(a2, b2, acc2, 0, 0, 0);
            acc3 = __builtin_amdgcn_mfma_f32_16x16x32_bf16(a3, b3, acc3, 0, 0, 0);
        }
        for (; j < m; ++j) {
            int A0 = __shfl(abo, j), B0 = __shfl(bfo, j);
            short8v a0 = *(const short8v*)(ab + A0 + aoff);
            short8v b0 = *(const short8v*)(bfrag + B0 + boff);
            acc0 = __builtin_amdgcn_mfma_f32_16x16x32_bf16(a0, b0, acc0, 0, 0, 0);
        }
    }
    f32x4 acc = (acc0 + acc1) + (acc2 + acc3);

    // combine halves through LDS (all waves reach the barrier)
    __shared__ f32x4 red[2][64];
    if (half) red[w >> 1][lane] = acc;
    __syncthreads();
    if (!half) {
        acc += red[w >> 1][lane];
        // D layout: col = lane&15, row = (lane>>4)*4 + q; cols 0..7 useful.
        int col = lane & 15;
        if (bag < B && col < 8) {
            int rb = (lane >> 4) * 4;
            float* orow = out + (size_t)bag * DIM;
#pragma unroll
            for (int q = 0; q < 4; ++q)
                orow[(rb + q) * 8 + col] = acc[q];   // d = m*8 + c3
        }
    }
}

// ---------------- fallback (ws too small): direct VALU, equal-length bags ----------------
__global__ __launch_bounds__(128) void fallback_pool(const int* __restrict__ indices,
                                                     int n, int B,
                                                     const float* __restrict__ core0,
                                                     const float* __restrict__ core1,
                                                     const float* __restrict__ core2,
                                                     float* __restrict__ out) {
    int bag = blockIdx.x;
    int d = threadIdx.x;
    int m = d >> 3, c3 = d & 7;
    int a_ = m >> 2, b_ = m & 3;
    int H = n / B;
    float acc = 0.f;
    for (int j = bag * H; j < (bag + 1) * H; ++j) {
        int idx = indices[j];
        int i1 = idx / (P1 * P2);
        int rem = idx - i1 * (P1 * P2);
        int i2 = rem / P2;
        int i3 = rem - i2 * P2;
        const float* a = core0 + (size_t)i1 * 128;
        const float* b = core1 + (size_t)i2 * 4096;
        const float* c = core2 + (size_t)i3 * 256;
        float e = 0.f;
        for (int s = 0; s < 32; ++s) {
            float abv = 0.f;
            for (int r = 0; r < 32; ++r)
                abv += a[a_ * 32 + r] * b[r * 128 + b_ * 32 + s];
            e += abv * c[s * 8 + c3];
        }
        acc += e;
    }
    out[(size_t)bag * DIM + d] = acc;
}

extern "C" void kernel_launch(void* const* d_in, const int* in_sizes, int n_in,
                              void* d_out, int out_size, void* d_ws, size_t ws_size,
                              hipStream_t stream) {
    const int* indices = (const int*)d_in[0];
    const int* lengths = (const int*)d_in[1];
    const float* core0 = (const float*)d_in[2];
    const float* core1 = (const float*)d_in[3];
    const float* core2 = (const float*)d_in[4];
    float* out = (float*)d_out;
    int n = in_sizes[0];
    int B = in_sizes[1];

    const size_t OFF_OFFSETS = 0;                       // (B+1) ints
    const size_t OFF_BFRAG = 32768;                     // 100 * 512 B
    const size_t OFF_AB = 131072;                       // 10000 * 1024 B
    const size_t REQ = OFF_AB + (size_t)NPAIR * 1024;

    if (ws_size >= REQ) {
        int* offsets = (int*)((char*)d_ws + OFF_OFFSETS);
        __hip_bfloat16* bfragp = (__hip_bfloat16*)((char*)d_ws + OFF_BFRAG);
        __hip_bfloat16* abt = (__hip_bfloat16*)((char*)d_ws + OFF_AB);

        prep<<<1 + P2 + 200, 256, 0, stream>>>(lengths, B, core0, core1, core2,
                                               offsets, bfragp, abt);
        bag_pool<<<(B + 1) / 2, 256, 0, stream>>>(indices, n, offsets, B,
                                                  (const char*)abt, (const char*)bfragp, out);
    } else {
        fallback_pool<<<B, 128, 0, stream>>>(indices, n, B, core0, core1, core2, out);
    }
}